// Round 3
// baseline (18571.797 us; speedup 1.0000x reference)
//
#include <hip/hip_runtime.h>
#include <hip/hip_bf16.h>

#define N_NODES 40962
#define N_EDGES 327680
#define NDIM 256
#define EDIM 64
#define HDIM 512
#define NLAYERS 16

using bf16_t = __bf16;
using bf16x4 = __bf16 __attribute__((ext_vector_type(4)));
using bf16x8 = __bf16 __attribute__((ext_vector_type(8)));
using f32x4  = float __attribute__((ext_vector_type(4)));

__device__ __forceinline__ void cvt_store4(bf16_t* p, float4 v) {
    bf16x4 t;
    t[0] = (bf16_t)v.x; t[1] = (bf16_t)v.y; t[2] = (bf16_t)v.z; t[3] = (bf16_t)v.w;
    *(bf16x4*)p = t;
}

__device__ __forceinline__ int clamp_idx(int v) {
    return v < 0 ? 0 : (v >= N_NODES ? N_NODES - 1 : v);
}

// ---------------------------------------------------------------------------
// Weight repack: W[l][k][n] (fp32, row-major KxN per layer) -> bf16 MFMA
// B-fragment order:
// dst[((l*tilesPer + (k0/32)*(N/16) + n0/16)*64 + lane)*8 + j]
//   = bf16(W[l][k0 + (lane>>4)*8 + j][n0 + (lane&15)])
// ---------------------------------------------------------------------------
__global__ void repack_w(const float* __restrict__ src, bf16_t* __restrict__ dst,
                         int K, int N, int tilesPer) {
    int idx = blockIdx.x * 256 + threadIdx.x;
    int lane = idx & 63;
    int t = idx >> 6;
    int l = t / tilesPer;
    int tile = t % tilesPer;
    if (l >= NLAYERS) return;
    int ntN = N >> 4;
    int k0 = (tile / ntN) << 5;
    int n0 = (tile % ntN) << 4;
    int k = k0 + (lane >> 4) * 8;
    int n = n0 + (lane & 15);
    const float* s = src + (size_t)l * K * N + (size_t)k * N + n;
    bf16x8 v;
#pragma unroll
    for (int j = 0; j < 8; ++j) v[j] = (bf16_t)s[(size_t)j * N];
    *(bf16x8*)(dst + (size_t)idx * 8) = v;
}

// edge features fp32 -> bf16 e-state, duplicated for both batch elements
__global__ void init_e2(const float* __restrict__ ef, bf16_t* __restrict__ es, int n8) {
    const size_t per = (size_t)N_EDGES * EDIM;
    for (int i = blockIdx.x * 256 + threadIdx.x; i < n8; i += gridDim.x * 256) {
        float4 a = *(const float4*)(ef + (size_t)i * 8);
        float4 b = *(const float4*)(ef + (size_t)i * 8 + 4);
        bf16x8 v;
        v[0] = (bf16_t)a.x; v[1] = (bf16_t)a.y; v[2] = (bf16_t)a.z; v[3] = (bf16_t)a.w;
        v[4] = (bf16_t)b.x; v[5] = (bf16_t)b.y; v[6] = (bf16_t)b.z; v[7] = (bf16_t)b.w;
        *(bf16x8*)(es + (size_t)i * 8) = v;
        *(bf16x8*)(es + per + (size_t)i * 8) = v;
    }
}

__global__ void zero_f32(float* __restrict__ p, int n4) {
    float4 z; z.x = z.y = z.z = z.w = 0.f;
    for (int i = blockIdx.x * 256 + threadIdx.x; i < n4; i += gridDim.x * 256)
        *(float4*)(p + (size_t)i * 4) = z;
}

// ---------------------------------------------------------------------------
// Edge kernel: per 64-edge tile, fused
//   m = [e | x[src] | x[dst]]  (K=576)
//   h = silu(m @ W1 + b1)      (512)
//   o = LN(h @ W2 + b2)*g + bl (64)
//   e += o (bf16 state) ; atomicAdd(agg[dst], e)
// LDS: A tile (64 x 584 bf16) aliased with H tile (64 x 520 bf16).
// ---------------------------------------------------------------------------
__global__ __launch_bounds__(256, 2)
void edge_kernel(const float* __restrict__ xs, bf16_t* __restrict__ es,
                 float* __restrict__ agg, const int* __restrict__ eidx,
                 const bf16_t* __restrict__ w1p, const float* __restrict__ b1,
                 const bf16_t* __restrict__ w2p, const float* __restrict__ b2,
                 const float* __restrict__ gw, const float* __restrict__ bw) {
    __shared__ bf16_t smem[64 * 584];   // A: stride 584; later H: stride 520
    __shared__ int sSrc[64], sDst[64];

    const int b   = blockIdx.y;
    const int e0  = blockIdx.x * 64;
    const int tid = threadIdx.x;

    const float* xb = xs + (size_t)b * N_NODES * NDIM;
    bf16_t* eb = es + (size_t)b * N_EDGES * EDIM;
    float* ab = agg + (size_t)b * N_NODES * EDIM;

    if (tid < 64) {
        sSrc[tid] = clamp_idx(eidx[e0 + tid]);
        sDst[tid] = clamp_idx(eidx[N_EDGES + e0 + tid]);
    }
    __syncthreads();

    // gather A = [e | x_src | x_dst]
    for (int i = tid; i < 64 * 8; i += 256) {      // e rows: bf16 direct copy
        int r = i >> 3, c = (i & 7) << 3;
        *(bf16x8*)&smem[r * 584 + c] = *(const bf16x8*)(eb + (size_t)(e0 + r) * EDIM + c);
    }
    for (int i = tid; i < 64 * 64; i += 256) {     // x_src fp32 -> bf16
        int r = i >> 6, f = (i & 63) << 2;
        float4 v = *(const float4*)(xb + (size_t)sSrc[r] * NDIM + f);
        cvt_store4(&smem[r * 584 + 64 + f], v);
    }
    for (int i = tid; i < 64 * 64; i += 256) {     // x_dst fp32 -> bf16
        int r = i >> 6, f = (i & 63) << 2;
        float4 v = *(const float4*)(xb + (size_t)sDst[r] * NDIM + f);
        cvt_store4(&smem[r * 584 + 320 + f], v);
    }
    __syncthreads();

    const int wv = tid >> 6, lane = tid & 63;
    const int m16 = lane & 15, quad = lane >> 4;

    // ---- MLP1: M=64, K=576, N=512. wave wv -> cols [wv*128, wv*128+128)
    f32x4 acc1[4][8];
#pragma unroll
    for (int mt = 0; mt < 4; ++mt)
#pragma unroll
        for (int nt = 0; nt < 8; ++nt) acc1[mt][nt] = (f32x4){0.f, 0.f, 0.f, 0.f};

    const bf16x8* W1 = (const bf16x8*)w1p;
#pragma unroll 2
    for (int kc = 0; kc < 18; ++kc) {
        bf16x8 af[4];
#pragma unroll
        for (int mt = 0; mt < 4; ++mt)
            af[mt] = *(const bf16x8*)&smem[(mt * 16 + m16) * 584 + kc * 32 + quad * 8];
        bf16x8 bfr[8];
#pragma unroll
        for (int nt = 0; nt < 8; ++nt)
            bfr[nt] = W1[(size_t)(kc * 32 + wv * 8 + nt) * 64 + lane];
#pragma unroll
        for (int mt = 0; mt < 4; ++mt)
#pragma unroll
            for (int nt = 0; nt < 8; ++nt)
                acc1[mt][nt] = __builtin_amdgcn_mfma_f32_16x16x32_bf16(af[mt], bfr[nt], acc1[mt][nt], 0, 0, 0);
    }
    __syncthreads();   // all waves done reading A before H aliases it

    float bias1[8];
#pragma unroll
    for (int nt = 0; nt < 8; ++nt) bias1[nt] = b1[wv * 128 + nt * 16 + m16];
#pragma unroll
    for (int mt = 0; mt < 4; ++mt)
#pragma unroll
        for (int nt = 0; nt < 8; ++nt)
#pragma unroll
            for (int r = 0; r < 4; ++r) {
                int row = mt * 16 + quad * 4 + r;
                int col = wv * 128 + nt * 16 + m16;
                float v = acc1[mt][nt][r] + bias1[nt];
                v = v / (1.f + __expf(-v));
                smem[row * 520 + col] = (bf16_t)v;
            }
    __syncthreads();

    // ---- MLP2: M=64, K=512, N=64. wave wv -> rows [wv*16, wv*16+16)
    f32x4 acc2[4];
#pragma unroll
    for (int nt = 0; nt < 4; ++nt) acc2[nt] = (f32x4){0.f, 0.f, 0.f, 0.f};
    const bf16x8* W2 = (const bf16x8*)w2p;
#pragma unroll 2
    for (int kc = 0; kc < 16; ++kc) {
        bf16x8 a2 = *(const bf16x8*)&smem[(wv * 16 + m16) * 520 + kc * 32 + quad * 8];
#pragma unroll
        for (int nt = 0; nt < 4; ++nt) {
            bf16x8 b2f = W2[(size_t)(kc * 4 + nt) * 64 + lane];
            acc2[nt] = __builtin_amdgcn_mfma_f32_16x16x32_bf16(a2, b2f, acc2[nt], 0, 0, 0);
        }
    }

    // epilogue: bias + LN(64) + residual + scatter
    float bias2[4], g4[4], bl4[4];
#pragma unroll
    for (int nt = 0; nt < 4; ++nt) {
        int c = nt * 16 + m16;
        bias2[nt] = b2[c];
        g4[nt]    = gw[c];
        bl4[nt]   = bw[c];
    }
#pragma unroll
    for (int r = 0; r < 4; ++r) {
        int row = wv * 16 + quad * 4 + r;
        float v[4], s1 = 0.f, s2 = 0.f;
#pragma unroll
        for (int nt = 0; nt < 4; ++nt) {
            v[nt] = acc2[nt][r] + bias2[nt];
            s1 += v[nt]; s2 += v[nt] * v[nt];
        }
#pragma unroll
        for (int off = 1; off < 16; off <<= 1) {
            s1 += __shfl_xor(s1, off);
            s2 += __shfl_xor(s2, off);
        }
        float mean = s1 * (1.f / 64.f);
        float var  = s2 * (1.f / 64.f) - mean * mean;
        float rstd = rsqrtf(fmaxf(var, 0.f) + 1e-5f);
        int eid = e0 + row;
        int d = sDst[row];
        bf16_t* ebr = eb + (size_t)eid * EDIM;
#pragma unroll
        for (int nt = 0; nt < 4; ++nt) {
            int c = nt * 16 + m16;
            float ln = (v[nt] - mean) * rstd * g4[nt] + bl4[nt];
            float en = (float)ebr[c] + ln;
            ebr[c] = (bf16_t)en;
            atomicAdd(&ab[(size_t)d * EDIM + c], en);
        }
    }
}

// ---------------------------------------------------------------------------
// Node kernel: per 64-node tile, fused
//   m = [x | agg]              (K=320)
//   h = silu(m @ W1 + b1)      (512)
//   x += LN(h @ W2 + b2)*g + bl (256)   — x-state lives in d_out (fp32)
// ---------------------------------------------------------------------------
__global__ __launch_bounds__(256, 2)
void node_kernel(float* __restrict__ xs, const float* __restrict__ agg,
                 const bf16_t* __restrict__ w1p, const float* __restrict__ b1,
                 const bf16_t* __restrict__ w2p, const float* __restrict__ b2,
                 const float* __restrict__ gw, const float* __restrict__ bw) {
    __shared__ bf16_t smem[64 * 520];   // A: stride 328; later H: stride 520

    const int b   = blockIdx.y;
    const int n0  = blockIdx.x * 64;
    const int tid = threadIdx.x;

    float* xb = xs + (size_t)b * N_NODES * NDIM;
    const float* ab = agg + (size_t)b * N_NODES * EDIM;

    float4 z4; z4.x = z4.y = z4.z = z4.w = 0.f;
    for (int i = tid; i < 64 * 64; i += 256) {
        int r = i >> 6, f = (i & 63) << 2;
        int node = n0 + r;
        float4 v = (node < N_NODES) ? *(const float4*)(xb + (size_t)node * NDIM + f) : z4;
        cvt_store4(&smem[r * 328 + f], v);
    }
    for (int i = tid; i < 64 * 16; i += 256) {
        int r = i >> 4, f = (i & 15) << 2;
        int node = n0 + r;
        float4 v = (node < N_NODES) ? *(const float4*)(ab + (size_t)node * EDIM + f) : z4;
        cvt_store4(&smem[r * 328 + 256 + f], v);
    }
    __syncthreads();

    const int wv = tid >> 6, lane = tid & 63;
    const int m16 = lane & 15, quad = lane >> 4;

    // ---- MLP1: M=64, K=320, N=512
    f32x4 acc1[4][8];
#pragma unroll
    for (int mt = 0; mt < 4; ++mt)
#pragma unroll
        for (int nt = 0; nt < 8; ++nt) acc1[mt][nt] = (f32x4){0.f, 0.f, 0.f, 0.f};

    const bf16x8* W1 = (const bf16x8*)w1p;
#pragma unroll 2
    for (int kc = 0; kc < 10; ++kc) {
        bf16x8 af[4];
#pragma unroll
        for (int mt = 0; mt < 4; ++mt)
            af[mt] = *(const bf16x8*)&smem[(mt * 16 + m16) * 328 + kc * 32 + quad * 8];
        bf16x8 bfr[8];
#pragma unroll
        for (int nt = 0; nt < 8; ++nt)
            bfr[nt] = W1[(size_t)(kc * 32 + wv * 8 + nt) * 64 + lane];
#pragma unroll
        for (int mt = 0; mt < 4; ++mt)
#pragma unroll
            for (int nt = 0; nt < 8; ++nt)
                acc1[mt][nt] = __builtin_amdgcn_mfma_f32_16x16x32_bf16(af[mt], bfr[nt], acc1[mt][nt], 0, 0, 0);
    }
    __syncthreads();

    float bias1[8];
#pragma unroll
    for (int nt = 0; nt < 8; ++nt) bias1[nt] = b1[wv * 128 + nt * 16 + m16];
#pragma unroll
    for (int mt = 0; mt < 4; ++mt)
#pragma unroll
        for (int nt = 0; nt < 8; ++nt)
#pragma unroll
            for (int r = 0; r < 4; ++r) {
                int row = mt * 16 + quad * 4 + r;
                int col = wv * 128 + nt * 16 + m16;
                float v = acc1[mt][nt][r] + bias1[nt];
                v = v / (1.f + __expf(-v));
                smem[row * 520 + col] = (bf16_t)v;
            }
    __syncthreads();

    // ---- MLP2: M=64, K=512, N=256. wave wv -> rows [wv*16, +16), all 256 cols
    f32x4 acc2[16];
#pragma unroll
    for (int nt = 0; nt < 16; ++nt) acc2[nt] = (f32x4){0.f, 0.f, 0.f, 0.f};
    const bf16x8* W2 = (const bf16x8*)w2p;
#pragma unroll 2
    for (int kc = 0; kc < 16; ++kc) {
        bf16x8 a2 = *(const bf16x8*)&smem[(wv * 16 + m16) * 520 + kc * 32 + quad * 8];
#pragma unroll
        for (int nt = 0; nt < 16; ++nt) {
            bf16x8 b2f = W2[(size_t)(kc * 16 + nt) * 64 + lane];
            acc2[nt] = __builtin_amdgcn_mfma_f32_16x16x32_bf16(a2, b2f, acc2[nt], 0, 0, 0);
        }
    }

    float bias2[16], g16[16], bl16[16];
#pragma unroll
    for (int nt = 0; nt < 16; ++nt) {
        int c = nt * 16 + m16;
        bias2[nt] = b2[c];
        g16[nt]   = gw[c];
        bl16[nt]  = bw[c];
    }
#pragma unroll
    for (int r = 0; r < 4; ++r) {
        int row = wv * 16 + quad * 4 + r;
        int node = n0 + row;
        if (node >= N_NODES) continue;
        float v[16], s1 = 0.f, s2 = 0.f;
#pragma unroll
        for (int nt = 0; nt < 16; ++nt) {
            v[nt] = acc2[nt][r] + bias2[nt];
            s1 += v[nt]; s2 += v[nt] * v[nt];
        }
#pragma unroll
        for (int off = 1; off < 16; off <<= 1) {
            s1 += __shfl_xor(s1, off);
            s2 += __shfl_xor(s2, off);
        }
        float mean = s1 * (1.f / 256.f);
        float var  = s2 * (1.f / 256.f) - mean * mean;
        float rstd = rsqrtf(fmaxf(var, 0.f) + 1e-5f);
#pragma unroll
        for (int nt = 0; nt < 16; ++nt) {
            int c = nt * 16 + m16;
            float ln = (v[nt] - mean) * rstd * g16[nt] + bl16[nt];
            xb[(size_t)node * NDIM + c] += ln;
        }
    }
}

extern "C" void kernel_launch(void* const* d_in, const int* in_sizes, int n_in,
                              void* d_out, int out_size, void* d_ws, size_t ws_size,
                              hipStream_t stream) {
    // ALL float tensors are fp32 per the reference (jnp.float32).
    const float* nf   = (const float*)d_in[0];
    const float* ef   = (const float*)d_in[1];
    const float* We1  = (const float*)d_in[2];
    const float* be1  = (const float*)d_in[3];
    const float* We2  = (const float*)d_in[4];
    const float* be2  = (const float*)d_in[5];
    const float* ge   = (const float*)d_in[6];
    const float* ble  = (const float*)d_in[7];
    const float* Wn1  = (const float*)d_in[8];
    const float* bn1  = (const float*)d_in[9];
    const float* Wn2  = (const float*)d_in[10];
    const float* bn2  = (const float*)d_in[11];
    const float* gn   = (const float*)d_in[12];
    const float* bln  = (const float*)d_in[13];
    const int* eidx   = (const int*)d_in[14];

    float* xs = (float*)d_out;   // x-state accumulates in-place in d_out (fp32)

    // workspace: 83.9 MB bf16 e-state + 21.0 MB fp32 agg + 19.9 MB bf16 weights
    char* p = (char*)d_ws;
    bf16_t* es = (bf16_t*)p; p += (size_t)2 * N_EDGES * EDIM * 2;
    float*  ag = (float*)p;  p += (size_t)2 * N_NODES * EDIM * 4;
    bf16_t* w1ep = (bf16_t*)p; p += (size_t)NLAYERS * 576 * 512 * 2;
    bf16_t* w2ep = (bf16_t*)p; p += (size_t)NLAYERS * 512 * 64 * 2;
    bf16_t* w1np = (bf16_t*)p; p += (size_t)NLAYERS * 320 * 512 * 2;
    bf16_t* w2np = (bf16_t*)p; p += (size_t)NLAYERS * 512 * 256 * 2;

    repack_w<<<2304, 256, 0, stream>>>(We1, w1ep, 576, 512, 576);
    repack_w<<<256,  256, 0, stream>>>(We2, w2ep, 512, 64,  64);
    repack_w<<<1280, 256, 0, stream>>>(Wn1, w1np, 320, 512, 320);
    repack_w<<<1024, 256, 0, stream>>>(Wn2, w2np, 512, 256, 256);

    hipMemcpyAsync(xs, nf, (size_t)out_size * 4, hipMemcpyDeviceToDevice, stream);
    init_e2<<<2048, 256, 0, stream>>>(ef, es, N_EDGES * EDIM / 8);

    for (int l = 0; l < NLAYERS; ++l) {
        zero_f32<<<2048, 256, 0, stream>>>(ag, 2 * N_NODES * EDIM / 4);
        edge_kernel<<<dim3(N_EDGES / 64, 2), 256, 0, stream>>>(
            xs, es, ag, eidx,
            w1ep + (size_t)l * 576 * 512, be1 + l * 512,
            w2ep + (size_t)l * 512 * 64,  be2 + l * 64,
            ge + l * 64, ble + l * 64);
        node_kernel<<<dim3((N_NODES + 63) / 64, 2), 256, 0, stream>>>(
            xs, ag,
            w1np + (size_t)l * 320 * 512, bn1 + l * 512,
            w2np + (size_t)l * 512 * 256, bn2 + l * 256,
            gn + l * 256, bln + l * 256);
    }
}

// Round 4
// 12979.982 us; speedup vs baseline: 1.4308x; 1.4308x over previous
//
#include <hip/hip_runtime.h>
#include <hip/hip_bf16.h>

#define N_NODES 40962
#define N_EDGES 327680
#define NDIM 256
#define EDIM 64
#define HDIM 512
#define NLAYERS 16

using bf16_t = __bf16;
using bf16x4 = __bf16 __attribute__((ext_vector_type(4)));
using bf16x8 = __bf16 __attribute__((ext_vector_type(8)));
using f32x4  = float __attribute__((ext_vector_type(4)));

__device__ __forceinline__ void cvt_store4(bf16_t* p, float4 v) {
    bf16x4 t;
    t[0] = (bf16_t)v.x; t[1] = (bf16_t)v.y; t[2] = (bf16_t)v.z; t[3] = (bf16_t)v.w;
    *(bf16x4*)p = t;
}

__device__ __forceinline__ int clamp_idx(int v) {
    return v < 0 ? 0 : (v >= N_NODES ? N_NODES - 1 : v);
}

// ---------------------------------------------------------------------------
// Weight repack: W[l][k][n] (fp32 KxN) -> bf16 MFMA B-fragment order.
// ---------------------------------------------------------------------------
__global__ void repack_w(const float* __restrict__ src, bf16_t* __restrict__ dst,
                         int K, int N, int tilesPer) {
    int idx = blockIdx.x * 256 + threadIdx.x;
    int lane = idx & 63;
    int t = idx >> 6;
    int l = t / tilesPer;
    int tile = t % tilesPer;
    if (l >= NLAYERS) return;
    int ntN = N >> 4;
    int k0 = (tile / ntN) << 5;
    int n0 = (tile % ntN) << 4;
    int k = k0 + (lane >> 4) * 8;
    int n = n0 + (lane & 15);
    const float* s = src + (size_t)l * K * N + (size_t)k * N + n;
    bf16x8 v;
#pragma unroll
    for (int j = 0; j < 8; ++j) v[j] = (bf16_t)s[(size_t)j * N];
    *(bf16x8*)(dst + (size_t)idx * 8) = v;
}

__global__ void init_e2(const float* __restrict__ ef, bf16_t* __restrict__ es, int n8) {
    const size_t per = (size_t)N_EDGES * EDIM;
    for (int i = blockIdx.x * 256 + threadIdx.x; i < n8; i += gridDim.x * 256) {
        float4 a = *(const float4*)(ef + (size_t)i * 8);
        float4 b = *(const float4*)(ef + (size_t)i * 8 + 4);
        bf16x8 v;
        v[0] = (bf16_t)a.x; v[1] = (bf16_t)a.y; v[2] = (bf16_t)a.z; v[3] = (bf16_t)a.w;
        v[4] = (bf16_t)b.x; v[5] = (bf16_t)b.y; v[6] = (bf16_t)b.z; v[7] = (bf16_t)b.w;
        *(bf16x8*)(es + (size_t)i * 8) = v;
        *(bf16x8*)(es + per + (size_t)i * 8) = v;
    }
}

__global__ void zero_f32(float* __restrict__ p, int n4) {
    float4 z; z.x = z.y = z.z = z.w = 0.f;
    for (int i = blockIdx.x * 256 + threadIdx.x; i < n4; i += gridDim.x * 256)
        *(float4*)(p + (size_t)i * 4) = z;
}

// ---------------------------------------------------------------------------
// Edge kernel, 512 threads (8 waves), 64-edge tile.
//   MLP1: wave wv -> cols [wv*64, +64)         (4 n-tiles, acc 16x f32x4)
//   MLP2: wave (strip=wv>>1, nh=wv&1) -> rows [strip*16,+16), cols [nh*32,+32)
//   LN(64) via m16-shuffle partials + LDS cross-wave combine.
// ---------------------------------------------------------------------------
__global__ __launch_bounds__(512, 4)
void edge_kernel(const float* __restrict__ xs, bf16_t* __restrict__ es,
                 float* __restrict__ agg, const int* __restrict__ eidx,
                 const bf16_t* __restrict__ w1p, const float* __restrict__ b1,
                 const bf16_t* __restrict__ w2p, const float* __restrict__ b2,
                 const float* __restrict__ gw, const float* __restrict__ bw) {
    __shared__ bf16_t smem[64 * 584];   // A: stride 584; later H: stride 520; tail: red
    __shared__ int sSrc[64], sDst[64];
    float* red = (float*)(smem + 64 * 520);   // 64 rows x 4 floats, in the tail

    const int b   = blockIdx.y;
    const int e0  = blockIdx.x * 64;
    const int tid = threadIdx.x;

    const float* xb = xs + (size_t)b * N_NODES * NDIM;
    bf16_t* eb = es + (size_t)b * N_EDGES * EDIM;
    float* ab = agg + (size_t)b * N_NODES * EDIM;

    if (tid < 64) {
        sSrc[tid] = clamp_idx(eidx[e0 + tid]);
        sDst[tid] = clamp_idx(eidx[N_EDGES + e0 + tid]);
    }
    __syncthreads();

    // gather A = [e | x_src | x_dst]
    {   // e rows: 512 bf16x8 chunks, exactly one per thread
        int r = tid >> 3, c = (tid & 7) << 3;
        *(bf16x8*)&smem[r * 584 + c] = *(const bf16x8*)(eb + (size_t)(e0 + r) * EDIM + c);
    }
#pragma unroll
    for (int k = 0; k < 8; ++k) {      // x_src: 64 rows x 16 float4
        int i = tid + k * 512;
        int r = i >> 6, f = (i & 63) << 2;
        float4 v = *(const float4*)(xb + (size_t)sSrc[r] * NDIM + f);
        cvt_store4(&smem[r * 584 + 64 + f], v);
    }
#pragma unroll
    for (int k = 0; k < 8; ++k) {      // x_dst
        int i = tid + k * 512;
        int r = i >> 6, f = (i & 63) << 2;
        float4 v = *(const float4*)(xb + (size_t)sDst[r] * NDIM + f);
        cvt_store4(&smem[r * 584 + 320 + f], v);
    }
    __syncthreads();

    const int wv = tid >> 6, lane = tid & 63;
    const int m16 = lane & 15, quad = lane >> 4;

    // ---- MLP1: M=64, K=576, N=512. wave wv -> cols [wv*64, +64)
    float bias1[4];
#pragma unroll
    for (int nt = 0; nt < 4; ++nt) bias1[nt] = b1[wv * 64 + nt * 16 + m16];

    f32x4 acc1[4][4];
#pragma unroll
    for (int mt = 0; mt < 4; ++mt)
#pragma unroll
        for (int nt = 0; nt < 4; ++nt) acc1[mt][nt] = (f32x4){0.f, 0.f, 0.f, 0.f};

    const bf16x8* W1 = (const bf16x8*)w1p;
#pragma unroll 2
    for (int kc = 0; kc < 18; ++kc) {
        bf16x8 af[4];
#pragma unroll
        for (int mt = 0; mt < 4; ++mt)
            af[mt] = *(const bf16x8*)&smem[(mt * 16 + m16) * 584 + kc * 32 + quad * 8];
        bf16x8 bfr[4];
#pragma unroll
        for (int nt = 0; nt < 4; ++nt)
            bfr[nt] = W1[(size_t)(kc * 32 + wv * 4 + nt) * 64 + lane];
#pragma unroll
        for (int mt = 0; mt < 4; ++mt)
#pragma unroll
            for (int nt = 0; nt < 4; ++nt)
                acc1[mt][nt] = __builtin_amdgcn_mfma_f32_16x16x32_bf16(af[mt], bfr[nt], acc1[mt][nt], 0, 0, 0);
    }
    __syncthreads();   // all waves done reading A before H aliases it

#pragma unroll
    for (int mt = 0; mt < 4; ++mt)
#pragma unroll
        for (int nt = 0; nt < 4; ++nt)
#pragma unroll
            for (int r = 0; r < 4; ++r) {
                int row = mt * 16 + quad * 4 + r;
                int col = wv * 64 + nt * 16 + m16;
                float v = acc1[mt][nt][r] + bias1[nt];
                v = v / (1.f + __expf(-v));
                smem[row * 520 + col] = (bf16_t)v;
            }
    __syncthreads();

    // ---- MLP2: M=64, K=512, N=64. wave (strip, nh): rows [strip*16,+16), cols [nh*32,+32)
    const int strip = wv >> 1, nh = wv & 1;
    f32x4 acc2[2];
#pragma unroll
    for (int nt = 0; nt < 2; ++nt) acc2[nt] = (f32x4){0.f, 0.f, 0.f, 0.f};
    const bf16x8* W2 = (const bf16x8*)w2p;
#pragma unroll 2
    for (int kc = 0; kc < 16; ++kc) {
        bf16x8 a2 = *(const bf16x8*)&smem[(strip * 16 + m16) * 520 + kc * 32 + quad * 8];
#pragma unroll
        for (int nt = 0; nt < 2; ++nt) {
            bf16x8 b2f = W2[(size_t)(kc * 4 + nh * 2 + nt) * 64 + lane];
            acc2[nt] = __builtin_amdgcn_mfma_f32_16x16x32_bf16(a2, b2f, acc2[nt], 0, 0, 0);
        }
    }

    // epilogue: bias + LN(64) partials (this wave covers 32 of 64 cols)
    float bias2[2], g2[2], bl2[2];
#pragma unroll
    for (int nt = 0; nt < 2; ++nt) {
        int c = nh * 32 + nt * 16 + m16;
        bias2[nt] = b2[c];
        g2[nt]    = gw[c];
        bl2[nt]   = bw[c];
    }
    float v[4][2];
#pragma unroll
    for (int r = 0; r < 4; ++r) {
        float s1 = 0.f, s2 = 0.f;
#pragma unroll
        for (int nt = 0; nt < 2; ++nt) {
            v[r][nt] = acc2[nt][r] + bias2[nt];
            s1 += v[r][nt]; s2 += v[r][nt] * v[r][nt];
        }
#pragma unroll
        for (int off = 1; off < 16; off <<= 1) {
            s1 += __shfl_xor(s1, off);
            s2 += __shfl_xor(s2, off);
        }
        if (m16 == 0) {
            int row = strip * 16 + quad * 4 + r;
            red[row * 4 + nh * 2 + 0] = s1;
            red[row * 4 + nh * 2 + 1] = s2;
        }
    }
    __syncthreads();

#pragma unroll
    for (int r = 0; r < 4; ++r) {
        int row = strip * 16 + quad * 4 + r;
        float s1 = red[row * 4 + 0] + red[row * 4 + 2];
        float s2 = red[row * 4 + 1] + red[row * 4 + 3];
        float mean = s1 * (1.f / 64.f);
        float var  = s2 * (1.f / 64.f) - mean * mean;
        float rstd = rsqrtf(fmaxf(var, 0.f) + 1e-5f);
        int eid = e0 + row;
        int d = sDst[row];
        bf16_t* ebr = eb + (size_t)eid * EDIM;
#pragma unroll
        for (int nt = 0; nt < 2; ++nt) {
            int c = nh * 32 + nt * 16 + m16;
            float ln = (v[r][nt] - mean) * rstd * g2[nt] + bl2[nt];
            float en = (float)ebr[c] + ln;
            ebr[c] = (bf16_t)en;
            atomicAdd(&ab[(size_t)d * EDIM + c], en);
        }
    }
}

// ---------------------------------------------------------------------------
// Node kernel, 512 threads (8 waves), 64-node tile.
//   MLP1: wave wv -> cols [wv*64,+64)
//   MLP2: wave (strip, nh) -> rows [strip*16,+16), cols [nh*128,+128)
// ---------------------------------------------------------------------------
__global__ __launch_bounds__(512, 4)
void node_kernel(float* __restrict__ xs, const float* __restrict__ agg,
                 const bf16_t* __restrict__ w1p, const float* __restrict__ b1,
                 const bf16_t* __restrict__ w2p, const float* __restrict__ b2,
                 const float* __restrict__ gw, const float* __restrict__ bw) {
    __shared__ bf16_t smem[64 * 528];   // A: stride 328; H: stride 520; tail: red
    float* red = (float*)(smem + 64 * 520);

    const int b   = blockIdx.y;
    const int n0  = blockIdx.x * 64;
    const int tid = threadIdx.x;

    float* xb = xs + (size_t)b * N_NODES * NDIM;
    const float* ab = agg + (size_t)b * N_NODES * EDIM;

    float4 z4; z4.x = z4.y = z4.z = z4.w = 0.f;
#pragma unroll
    for (int k = 0; k < 8; ++k) {      // x: 64 rows x 64 float4
        int i = tid + k * 512;
        int r = i >> 6, f = (i & 63) << 2;
        int node = n0 + r;
        float4 v = (node < N_NODES) ? *(const float4*)(xb + (size_t)node * NDIM + f) : z4;
        cvt_store4(&smem[r * 328 + f], v);
    }
#pragma unroll
    for (int k = 0; k < 2; ++k) {      // agg: 64 rows x 16 float4
        int i = tid + k * 512;
        int r = i >> 4, f = (i & 15) << 2;
        int node = n0 + r;
        float4 v = (node < N_NODES) ? *(const float4*)(ab + (size_t)node * EDIM + f) : z4;
        cvt_store4(&smem[r * 328 + 256 + f], v);
    }
    __syncthreads();

    const int wv = tid >> 6, lane = tid & 63;
    const int m16 = lane & 15, quad = lane >> 4;

    // ---- MLP1: M=64, K=320, N=512
    float bias1[4];
#pragma unroll
    for (int nt = 0; nt < 4; ++nt) bias1[nt] = b1[wv * 64 + nt * 16 + m16];

    f32x4 acc1[4][4];
#pragma unroll
    for (int mt = 0; mt < 4; ++mt)
#pragma unroll
        for (int nt = 0; nt < 4; ++nt) acc1[mt][nt] = (f32x4){0.f, 0.f, 0.f, 0.f};

    const bf16x8* W1 = (const bf16x8*)w1p;
#pragma unroll 2
    for (int kc = 0; kc < 10; ++kc) {
        bf16x8 af[4];
#pragma unroll
        for (int mt = 0; mt < 4; ++mt)
            af[mt] = *(const bf16x8*)&smem[(mt * 16 + m16) * 328 + kc * 32 + quad * 8];
        bf16x8 bfr[4];
#pragma unroll
        for (int nt = 0; nt < 4; ++nt)
            bfr[nt] = W1[(size_t)(kc * 32 + wv * 4 + nt) * 64 + lane];
#pragma unroll
        for (int mt = 0; mt < 4; ++mt)
#pragma unroll
            for (int nt = 0; nt < 4; ++nt)
                acc1[mt][nt] = __builtin_amdgcn_mfma_f32_16x16x32_bf16(af[mt], bfr[nt], acc1[mt][nt], 0, 0, 0);
    }
    __syncthreads();

#pragma unroll
    for (int mt = 0; mt < 4; ++mt)
#pragma unroll
        for (int nt = 0; nt < 4; ++nt)
#pragma unroll
            for (int r = 0; r < 4; ++r) {
                int row = mt * 16 + quad * 4 + r;
                int col = wv * 64 + nt * 16 + m16;
                float v = acc1[mt][nt][r] + bias1[nt];
                v = v / (1.f + __expf(-v));
                smem[row * 520 + col] = (bf16_t)v;
            }
    __syncthreads();

    // ---- MLP2: M=64, K=512, N=256. wave (strip, nh): rows [strip*16,+16), cols [nh*128,+128)
    const int strip = wv >> 1, nh = wv & 1;
    f32x4 acc2[8];
#pragma unroll
    for (int nt = 0; nt < 8; ++nt) acc2[nt] = (f32x4){0.f, 0.f, 0.f, 0.f};
    const bf16x8* W2 = (const bf16x8*)w2p;
#pragma unroll 2
    for (int kc = 0; kc < 16; ++kc) {
        bf16x8 a2 = *(const bf16x8*)&smem[(strip * 16 + m16) * 520 + kc * 32 + quad * 8];
#pragma unroll
        for (int nt = 0; nt < 8; ++nt) {
            bf16x8 b2f = W2[(size_t)(kc * 16 + nh * 8 + nt) * 64 + lane];
            acc2[nt] = __builtin_amdgcn_mfma_f32_16x16x32_bf16(a2, b2f, acc2[nt], 0, 0, 0);
        }
    }

    float bias2[8], g8[8], bl8[8];
#pragma unroll
    for (int nt = 0; nt < 8; ++nt) {
        int c = nh * 128 + nt * 16 + m16;
        bias2[nt] = b2[c];
        g8[nt]    = gw[c];
        bl8[nt]   = bw[c];
    }
    float v[4][8];
#pragma unroll
    for (int r = 0; r < 4; ++r) {
        float s1 = 0.f, s2 = 0.f;
#pragma unroll
        for (int nt = 0; nt < 8; ++nt) {
            v[r][nt] = acc2[nt][r] + bias2[nt];
            s1 += v[r][nt]; s2 += v[r][nt] * v[r][nt];
        }
#pragma unroll
        for (int off = 1; off < 16; off <<= 1) {
            s1 += __shfl_xor(s1, off);
            s2 += __shfl_xor(s2, off);
        }
        if (m16 == 0) {
            int row = strip * 16 + quad * 4 + r;
            red[row * 4 + nh * 2 + 0] = s1;
            red[row * 4 + nh * 2 + 1] = s2;
        }
    }
    __syncthreads();

#pragma unroll
    for (int r = 0; r < 4; ++r) {
        int row = strip * 16 + quad * 4 + r;
        int node = n0 + row;
        if (node >= N_NODES) continue;
        float s1 = red[row * 4 + 0] + red[row * 4 + 2];
        float s2 = red[row * 4 + 1] + red[row * 4 + 3];
        float mean = s1 * (1.f / 256.f);
        float var  = s2 * (1.f / 256.f) - mean * mean;
        float rstd = rsqrtf(fmaxf(var, 0.f) + 1e-5f);
#pragma unroll
        for (int nt = 0; nt < 8; ++nt) {
            int c = nh * 128 + nt * 16 + m16;
            float ln = (v[r][nt] - mean) * rstd * g8[nt] + bl8[nt];
            xb[(size_t)node * NDIM + c] += ln;
        }
    }
}

extern "C" void kernel_launch(void* const* d_in, const int* in_sizes, int n_in,
                              void* d_out, int out_size, void* d_ws, size_t ws_size,
                              hipStream_t stream) {
    const float* nf   = (const float*)d_in[0];
    const float* ef   = (const float*)d_in[1];
    const float* We1  = (const float*)d_in[2];
    const float* be1  = (const float*)d_in[3];
    const float* We2  = (const float*)d_in[4];
    const float* be2  = (const float*)d_in[5];
    const float* ge   = (const float*)d_in[6];
    const float* ble  = (const float*)d_in[7];
    const float* Wn1  = (const float*)d_in[8];
    const float* bn1  = (const float*)d_in[9];
    const float* Wn2  = (const float*)d_in[10];
    const float* bn2  = (const float*)d_in[11];
    const float* gn   = (const float*)d_in[12];
    const float* bln  = (const float*)d_in[13];
    const int* eidx   = (const int*)d_in[14];

    float* xs = (float*)d_out;   // x-state accumulates in-place in d_out (fp32)

    char* p = (char*)d_ws;
    bf16_t* es = (bf16_t*)p; p += (size_t)2 * N_EDGES * EDIM * 2;
    float*  ag = (float*)p;  p += (size_t)2 * N_NODES * EDIM * 4;
    bf16_t* w1ep = (bf16_t*)p; p += (size_t)NLAYERS * 576 * 512 * 2;
    bf16_t* w2ep = (bf16_t*)p; p += (size_t)NLAYERS * 512 * 64 * 2;
    bf16_t* w1np = (bf16_t*)p; p += (size_t)NLAYERS * 320 * 512 * 2;
    bf16_t* w2np = (bf16_t*)p; p += (size_t)NLAYERS * 512 * 256 * 2;

    repack_w<<<2304, 256, 0, stream>>>(We1, w1ep, 576, 512, 576);
    repack_w<<<256,  256, 0, stream>>>(We2, w2ep, 512, 64,  64);
    repack_w<<<1280, 256, 0, stream>>>(Wn1, w1np, 320, 512, 320);
    repack_w<<<1024, 256, 0, stream>>>(Wn2, w2np, 512, 256, 256);

    hipMemcpyAsync(xs, nf, (size_t)out_size * 4, hipMemcpyDeviceToDevice, stream);
    init_e2<<<2048, 256, 0, stream>>>(ef, es, N_EDGES * EDIM / 8);

    for (int l = 0; l < NLAYERS; ++l) {
        zero_f32<<<2048, 256, 0, stream>>>(ag, 2 * N_NODES * EDIM / 4);
        edge_kernel<<<dim3(N_EDGES / 64, 2), 512, 0, stream>>>(
            xs, es, ag, eidx,
            w1ep + (size_t)l * 576 * 512, be1 + l * 512,
            w2ep + (size_t)l * 512 * 64,  be2 + l * 64,
            ge + l * 64, ble + l * 64);
        node_kernel<<<dim3((N_NODES + 63) / 64, 2), 512, 0, stream>>>(
            xs, ag,
            w1np + (size_t)l * 320 * 512, bn1 + l * 512,
            w2np + (size_t)l * 512 * 256, bn2 + l * 256,
            gn + l * 256, bln + l * 256);
    }
}